// Round 2
// baseline (156.288 us; speedup 1.0000x reference)
//
#include <hip/hip_runtime.h>
#include <stdint.h>

#define NB 512      // batch
#define NFEAT 8192
#define NG 512      // groups
#define GG 64       // gather size / K
#define DD 128      // out features per group

typedef float f32x4 __attribute__((ext_vector_type(4)));

// xT[c][b] = x[b][c], f32, via LDS tile transpose (coalesced both sides)
__global__ __launch_bounds__(256) void transpose_x(const float* __restrict__ x,
                                                   float* __restrict__ xT) {
  __shared__ float t[64][65];
  const int c0 = blockIdx.x * 64;
  const int b0 = blockIdx.y * 64;
  const int tid = threadIdx.x;
  const int col = tid & 63;
  const int rg = tid >> 6;            // 0..3
  #pragma unroll
  for (int r = 0; r < 16; ++r) {
    int row = rg * 16 + r;            // b-local
    t[col][row] = x[(size_t)(b0 + row) * NFEAT + c0 + col];
  }
  __syncthreads();
  #pragma unroll
  for (int r = 0; r < 16; ++r) {
    int crow = rg * 16 + r;           // c-local
    xT[(size_t)(c0 + crow) * NB + b0 + col] = t[crow][col];
  }
}

// One thread = (b, n, d-half). 128 threads/block = 2 waves (dh 0/1), 64 b-rows.
// W rows are wave-uniform -> scalar loads; x gather coalesced via xT.
__global__ __launch_bounds__(128) void lc_f32(
    const float* __restrict__ xT,
    const float* __restrict__ W,
    const int* __restrict__ idx,
    const float* __restrict__ bias,
    const float* __restrict__ gamma,
    const float* __restrict__ beta,
    float* __restrict__ out) {
  __shared__ __attribute__((aligned(16))) float ot[64][132];  // [b-local][d], padded
  __shared__ float part[2][64][2];

  const int n = blockIdx.x;
  const int b0 = blockIdx.y * 64;
  const int tid = threadIdx.x;
  const int lane = tid & 63;
  const int dh = __builtin_amdgcn_readfirstlane(tid >> 6);    // 0/1, wave-uniform SGPR
  const int b = b0 + lane;

  const int* idxn = idx + n * GG;
  const float* wbase = W + (size_t)n * (GG * DD) + dh * 64;

  float acc[64];
  #pragma unroll
  for (int j = 0; j < 64; ++j) acc[j] = 0.f;

  #pragma unroll 2
  for (int g = 0; g < GG; ++g) {
    const int c = idxn[g];                       // uniform -> s_load
    const float xv = xT[(size_t)c * NB + b];     // coalesced 256B/wave
    const float* wr = wbase + (size_t)g * DD;    // uniform row -> s_loads
    #pragma unroll
    for (int j = 0; j < 64; ++j) acc[j] = fmaf(xv, wr[j], acc[j]);
  }

  // bias + LeakyReLU + partial LN stats
  float sum = 0.f, sum2 = 0.f;
  const float* brow = bias + n * DD + dh * 64;
  #pragma unroll
  for (int j = 0; j < 64; ++j) {
    float h = acc[j] + brow[j];
    h = (h >= 0.f) ? h : 0.2f * h;
    acc[j] = h;
    sum += h;
    sum2 += h * h;
  }
  part[dh][lane][0] = sum;
  part[dh][lane][1] = sum2;
  __syncthreads();
  const float ts  = part[0][lane][0] + part[1][lane][0];
  const float ts2 = part[0][lane][1] + part[1][lane][1];
  const float mu  = ts * (1.f / 128.f);
  const float var = ts2 * (1.f / 128.f) - mu * mu;
  const float rs  = rsqrtf(var + 1e-5f);

  // stage normalized values
  #pragma unroll
  for (int j4 = 0; j4 < 16; ++j4) {
    f32x4 v;
    v.x = (acc[4 * j4 + 0] - mu) * rs;
    v.y = (acc[4 * j4 + 1] - mu) * rs;
    v.z = (acc[4 * j4 + 2] - mu) * rs;
    v.w = (acc[4 * j4 + 3] - mu) * rs;
    *(f32x4*)&ot[lane][dh * 64 + 4 * j4] = v;
  }
  __syncthreads();

  // cooperative coalesced write: each instr covers 2 rows x 512B, gamma/beta applied
  const int cch = lane & 31;          // d-chunk (4 f32)
  const int half = lane >> 5;
  const f32x4 gm = *(const f32x4*)(gamma + cch * 4);
  const f32x4 bt = *(const f32x4*)(beta + cch * 4);
  #pragma unroll
  for (int k = 0; k < 32; ++k) {
    int R = k * 2 + half;
    f32x4 v = *(const f32x4*)&ot[R][cch * 4];
    v = v * gm + bt;
    *(f32x4*)(out + ((size_t)(b0 + R) * NG + n) * DD + cch * 4) = v;
  }
}

extern "C" void kernel_launch(void* const* d_in, const int* in_sizes, int n_in,
                              void* d_out, int out_size, void* d_ws, size_t ws_size,
                              hipStream_t stream) {
  const float* x     = (const float*)d_in[0];
  const int*   idx   = (const int*)d_in[1];
  const float* W     = (const float*)d_in[2];
  const float* bias  = (const float*)d_in[3];
  const float* gamma = (const float*)d_in[4];
  const float* beta  = (const float*)d_in[5];
  float* out = (float*)d_out;

  float* xT = (float*)d_ws;                      // 8192*512 f32 = 16 MiB

  transpose_x<<<dim3(NFEAT / 64, NB / 64), 256, 0, stream>>>(x, xT);
  lc_f32<<<dim3(NG, NB / 64), 128, 0, stream>>>(xT, W, idx, bias, gamma, beta, out);
}